// Round 1
// baseline (437.976 us; speedup 1.0000x reference)
//
#include <hip/hip_runtime.h>

// Problem constants
#define B_      32
#define C_COMB  448
#define P32_    1024   // 32x32 positions
#define N_POS_  4096   // 64x64 positions
#define D_      100
#define OUT_HW_ 256

// ---------------------------------------------------------------------------
// Kernel 1: transpose mean [100][4096] -> meanT [4096][100]
// ---------------------------------------------------------------------------
__global__ __launch_bounds__(256) void k_transpose_mean(const float* __restrict__ mean,
                                                        float* __restrict__ meanT) {
    int i = blockIdx.x * 256 + threadIdx.x;        // coalesced read over input
    if (i < D_ * N_POS_) {
        int d = i >> 12;       // / 4096
        int n = i & 4095;
        meanT[n * D_ + d] = mean[i];
    }
}

// ---------------------------------------------------------------------------
// Kernel 2: projection GEMM at 32x32:
//   p32[pos][b][d] = sum_c W[d][c] * combined[b][c][pos] + bias[d]
// Block: 64 pos x 100 d for one batch b. Thread tile: 4 pos x 7 d.
// ---------------------------------------------------------------------------
__global__ __launch_bounds__(256) void k_proj(const float* __restrict__ comb,
                                              const float* __restrict__ W,
                                              const float* __restrict__ bias,
                                              float* __restrict__ p32) {
    __shared__ float As[32 * 64];     // [cc][p]     8 KB
    __shared__ float Ws[32 * 113];    // [cc][d] pad 14.1 KB (stride 113 kills store conflicts)

    const int b    = blockIdx.y;
    const int pos0 = blockIdx.x * 64;
    const int t    = threadIdx.x;
    const int tx   = t & 15;          // pos quad: 4*tx .. 4*tx+3
    const int ty   = t >> 4;          // d: ty + 16*j, j<7

    float acc[7][4];
#pragma unroll
    for (int j = 0; j < 7; j++)
#pragma unroll
        for (int q = 0; q < 4; q++) acc[j][q] = 0.f;

    const float4* comb4 = (const float4*)comb;
    const float4* W4    = (const float4*)W;

    for (int c0 = 0; c0 < C_COMB; c0 += 32) {
        __syncthreads();
        // A chunk: 32 c x 64 pos = 512 float4, coalesced
#pragma unroll
        for (int k = 0; k < 2; k++) {
            int e4 = t + 256 * k;
            int cc = e4 >> 4, p4 = e4 & 15;
            float4 v = comb4[(b * C_COMB + c0 + cc) * 256 + (pos0 >> 2) + p4];
            ((float4*)As)[cc * 16 + p4] = v;
        }
        // W chunk: 100 d x 32 c = 800 float4, coalesced; store transposed [cc][d]
#pragma unroll
        for (int k = 0; k < 4; k++) {
            int e4 = t + 256 * k;
            if (e4 < 800) {
                int d = e4 >> 3, cq = e4 & 7;
                float4 v = W4[d * 112 + (c0 >> 2) + cq];
                Ws[(4 * cq + 0) * 113 + d] = v.x;
                Ws[(4 * cq + 1) * 113 + d] = v.y;
                Ws[(4 * cq + 2) * 113 + d] = v.z;
                Ws[(4 * cq + 3) * 113 + d] = v.w;
            }
        }
        __syncthreads();
#pragma unroll 4
        for (int cc = 0; cc < 32; cc++) {
            float4 a = ((const float4*)As)[cc * 16 + tx];   // b128, contiguous window
#pragma unroll
            for (int j = 0; j < 7; j++) {
                float w = Ws[cc * 113 + ty + 16 * j];       // broadcast within wave
                acc[j][0] = fmaf(w, a.x, acc[j][0]);
                acc[j][1] = fmaf(w, a.y, acc[j][1]);
                acc[j][2] = fmaf(w, a.z, acc[j][2]);
                acc[j][3] = fmaf(w, a.w, acc[j][3]);
            }
        }
    }
    // store: p32[pos][b][d]
#pragma unroll
    for (int j = 0; j < 7; j++) {
        int d = ty + 16 * j;
        if (d < D_) {
            float pb = bias[d];
#pragma unroll
            for (int q = 0; q < 4; q++) {
                int pos = pos0 + 4 * tx + q;
                p32[pos * (B_ * D_) + b * D_ + d] = acc[j][q] + pb;
            }
        }
    }
}

// ---------------------------------------------------------------------------
// Kernel 3: per output position n (64x64): fused 2x bilinear upsample of p32,
// mean subtract, and Mahalanobis quadratic form for all 32 batches.
// ---------------------------------------------------------------------------
#define DT_STRIDE 36   // pad: (36j+4q)*4B is 16B-aligned -> b128 reads OK

__device__ __forceinline__ void row_fma(float (&a)[4], const float* Mrow,
                                        const float4& d0, const float4& d1,
                                        const float4& d2, const float4& d3) {
    float4 m = *(const float4*)Mrow;
    a[0] = fmaf(m.x, d0.x, a[0]); a[0] = fmaf(m.y, d1.x, a[0]);
    a[0] = fmaf(m.z, d2.x, a[0]); a[0] = fmaf(m.w, d3.x, a[0]);
    a[1] = fmaf(m.x, d0.y, a[1]); a[1] = fmaf(m.y, d1.y, a[1]);
    a[1] = fmaf(m.z, d2.y, a[1]); a[1] = fmaf(m.w, d3.y, a[1]);
    a[2] = fmaf(m.x, d0.z, a[2]); a[2] = fmaf(m.y, d1.z, a[2]);
    a[2] = fmaf(m.z, d2.z, a[2]); a[2] = fmaf(m.w, d3.z, a[2]);
    a[3] = fmaf(m.x, d0.w, a[3]); a[3] = fmaf(m.y, d1.w, a[3]);
    a[3] = fmaf(m.z, d2.w, a[3]); a[3] = fmaf(m.w, d3.w, a[3]);
}

__global__ __launch_bounds__(256) void k_mahal(const float* __restrict__ p32,
                                               const float* __restrict__ meanT,
                                               const float* __restrict__ icov,
                                               float* __restrict__ gdist) {
    __shared__ float Ml[D_ * D_];           // 40000 B
    __shared__ float dT[D_ * DT_STRIDE];    // 14400 B, dT[d][b] padded

    const int n = blockIdx.x;
    const int t = threadIdx.x;

    // bilinear 32->64 source (half-pixel, clamp == jax renormalized boundary)
    const int y = n >> 6, x = n & 63;
    float sy = 0.5f * y - 0.25f, sx = 0.5f * x - 0.25f;
    float y0f = floorf(sy), x0f = floorf(sx);
    float fy = sy - y0f, fx = sx - x0f;
    int iy0 = max((int)y0f, 0), iy1 = min((int)y0f + 1, 31);
    int ix0 = max((int)x0f, 0), ix1 = min((int)x0f + 1, 31);
    const float w00 = (1.f - fy) * (1.f - fx), w01 = (1.f - fy) * fx;
    const float w10 = fy * (1.f - fx),         w11 = fy * fx;
    const float* s00 = p32 + (iy0 * 32 + ix0) * (B_ * D_);
    const float* s01 = p32 + (iy0 * 32 + ix1) * (B_ * D_);
    const float* s10 = p32 + (iy1 * 32 + ix0) * (B_ * D_);
    const float* s11 = p32 + (iy1 * 32 + ix1) * (B_ * D_);

    // stage Sigma^-1[n] (40 KB) into LDS, coalesced float4
    const float4* gM4 = (const float4*)(icov + (size_t)n * (D_ * D_));
    float4* Ml4 = (float4*)Ml;
#pragma unroll
    for (int k = 0; k < 10; k++) {
        int e4 = t + 256 * k;
        if (e4 < 2500) Ml4[e4] = gM4[e4];
    }
    // diff tile: e enumerates (b,d) contiguously -> global reads fully coalesced
    const float* mt = meanT + n * D_;
#pragma unroll
    for (int k = 0; k < 13; k++) {
        int e = t + 256 * k;
        if (e < 3200) {
            unsigned b = (unsigned)e / 100u;
            unsigned d = (unsigned)e - b * 100u;
            float v = w00 * s00[e] + w01 * s01[e] + w10 * s10[e] + w11 * s11[e] - mt[d];
            dT[d * DT_STRIDE + b] = v;
        }
    }
    __syncthreads();

    // compute: thread owns 4 batches (b4) x rows {ig, ig+32, ig+64 [, ig+96]}
    const int b4 = t & 7;        // batches 4*b4 .. 4*b4+3
    const int ig = t >> 3;       // 0..31
    float acc[4][4] = {{0,0,0,0},{0,0,0,0},{0,0,0,0},{0,0,0,0}};
    const float4* dT4 = (const float4*)dT;   // row j at float4 index 9*j

    for (int j4 = 0; j4 < 25; j4++) {
        const int j = 4 * j4;
        float4 dva = dT4[9 * j + b4];
        float4 dvb = dT4[9 * j + 9 + b4];
        float4 dvc = dT4[9 * j + 18 + b4];
        float4 dvd = dT4[9 * j + 27 + b4];
#pragma unroll
        for (int r = 0; r < 3; r++) {
            row_fma(acc[r], &Ml[(32 * r + ig) * D_ + j], dva, dvb, dvc, dvd);
        }
        if (ig < 4) {   // row 96+ig; waves 1-3 skip entirely (wave-uniform there)
            row_fma(acc[3], &Ml[(96 + ig) * D_ + j], dva, dvb, dvc, dvd);
        }
    }

    // fold: dist_q = sum_r acc[r][q] * d[b_q][i_r]
    float dist[4] = {0, 0, 0, 0};
#pragma unroll
    for (int r = 0; r < 3; r++) {
        float4 dd = dT4[9 * (32 * r + ig) + b4];
        dist[0] = fmaf(acc[r][0], dd.x, dist[0]);
        dist[1] = fmaf(acc[r][1], dd.y, dist[1]);
        dist[2] = fmaf(acc[r][2], dd.z, dist[2]);
        dist[3] = fmaf(acc[r][3], dd.w, dist[3]);
    }
    if (ig < 4) {
        float4 dd = dT4[9 * (96 + ig) + b4];
        dist[0] = fmaf(acc[3][0], dd.x, dist[0]);
        dist[1] = fmaf(acc[3][1], dd.y, dist[1]);
        dist[2] = fmaf(acc[3][2], dd.z, dist[2]);
        dist[3] = fmaf(acc[3][3], dd.w, dist[3]);
    }

    // reduce over ig within wave: xor bits 3,4,5 (keeps b4 = lane&7 fixed)
#pragma unroll
    for (int off = 8; off < 64; off <<= 1) {
        dist[0] += __shfl_xor(dist[0], off);
        dist[1] += __shfl_xor(dist[1], off);
        dist[2] += __shfl_xor(dist[2], off);
        dist[3] += __shfl_xor(dist[3], off);
    }

    __syncthreads();               // all waves done reading Ml; reuse as scratch
    float* part = Ml;              // [4 waves][32 b]
    const int lane = t & 63, w = t >> 6;
    if (lane < 8) {                // lane == b4 here
        part[w * 32 + 4 * lane + 0] = dist[0];
        part[w * 32 + 4 * lane + 1] = dist[1];
        part[w * 32 + 4 * lane + 2] = dist[2];
        part[w * 32 + 4 * lane + 3] = dist[3];
    }
    __syncthreads();
    if (t < 32) {
        float s = part[t] + part[32 + t] + part[64 + t] + part[96 + t];
        gdist[t * N_POS_ + n] = s;     // dist[b][64][64]
    }
}

// ---------------------------------------------------------------------------
// Kernel 4: 4x bilinear upsample 64->256 + normalization, one thread/pixel
// ---------------------------------------------------------------------------
__global__ __launch_bounds__(256) void k_upsample(const float* __restrict__ gdist,
                                                  const float* __restrict__ nminp,
                                                  const float* __restrict__ nmaxp,
                                                  float* __restrict__ out) {
    int gid = blockIdx.x * 256 + threadIdx.x;   // 32*256*256 exact
    int b   = gid >> 16;
    int rem = gid & 65535;
    int Y = rem >> 8, X = rem & 255;
    float sy = 0.25f * Y - 0.375f, sx = 0.25f * X - 0.375f;
    float y0f = floorf(sy), x0f = floorf(sx);
    float fy = sy - y0f, fx = sx - x0f;
    int iy0 = max((int)y0f, 0), iy1 = min((int)y0f + 1, 63);
    int ix0 = max((int)x0f, 0), ix1 = min((int)x0f + 1, 63);
    const float* g = gdist + b * N_POS_;
    float v00 = g[iy0 * 64 + ix0], v01 = g[iy0 * 64 + ix1];
    float v10 = g[iy1 * 64 + ix0], v11 = g[iy1 * 64 + ix1];
    float v = (1.f - fy) * ((1.f - fx) * v00 + fx * v01)
            +        fy  * ((1.f - fx) * v10 + fx * v11);
    float nmin = nminp[0], nmax = nmaxp[0];
    float scale = 1.0f / (nmax - nmin + 1e-8f);
    out[gid] = (v - nmin) * scale;
}

// ---------------------------------------------------------------------------
extern "C" void kernel_launch(void* const* d_in, const int* in_sizes, int n_in,
                              void* d_out, int out_size, void* d_ws, size_t ws_size,
                              hipStream_t stream) {
    const float* comb = (const float*)d_in[0];
    const float* W    = (const float*)d_in[1];
    const float* bias = (const float*)d_in[2];
    const float* mean = (const float*)d_in[3];
    const float* icov = (const float*)d_in[4];
    const float* nmin = (const float*)d_in[5];
    const float* nmax = (const float*)d_in[6];
    float* out = (float*)d_out;

    char* ws = (char*)d_ws;
    float* p32   = (float*)(ws);                          // 1024*32*100*4 = 13,107,200 B
    float* meanT = (float*)(ws + 13107200);               // 4096*100*4    =  1,638,400 B
    float* gdist = (float*)(ws + 13107200 + 1638400);     // 32*4096*4     =    524,288 B

    k_transpose_mean<<<1600, 256, 0, stream>>>(mean, meanT);
    k_proj<<<dim3(16, 32), 256, 0, stream>>>(comb, W, bias, p32);
    k_mahal<<<4096, 256, 0, stream>>>(p32, meanT, icov, gdist);
    k_upsample<<<8192, 256, 0, stream>>>(gdist, nmin, nmax, out);
}

// Round 2
// 350.261 us; speedup vs baseline: 1.2504x; 1.2504x over previous
//
#include <hip/hip_runtime.h>

#define B_      32
#define C_COMB  448
#define N_POS_  4096
#define D_      100

typedef __attribute__((ext_vector_type(8))) short bf16x8;
typedef __attribute__((ext_vector_type(4))) float f32x4;

// ---------------- bf16 helpers (RNE) ----------------
__device__ __forceinline__ unsigned short f2bf(float f) {
    unsigned u = __builtin_bit_cast(unsigned, f);
    u += 0x7FFFu + ((u >> 16) & 1u);
    return (unsigned short)(u >> 16);
}
__device__ __forceinline__ unsigned pack2bf(float a, float b) {
    return (unsigned)f2bf(a) | ((unsigned)f2bf(b) << 16);
}
__device__ __forceinline__ float bf2f(unsigned short h) {
    return __builtin_bit_cast(float, (unsigned)h << 16);
}
__device__ __forceinline__ float4 bf4_to_f4(uint2 u) {
    float4 r;
    r.x = __builtin_bit_cast(float, u.x << 16);
    r.y = __builtin_bit_cast(float, u.x & 0xffff0000u);
    r.z = __builtin_bit_cast(float, u.y << 16);
    r.w = __builtin_bit_cast(float, u.y & 0xffff0000u);
    return r;
}
// async global->LDS DMA, 16B per lane, wave-uniform base + lane*16
__device__ __forceinline__ void async_copy16(const void* g, void* lds) {
    __builtin_amdgcn_global_load_lds(
        (const __attribute__((address_space(1))) unsigned int*)g,
        (__attribute__((address_space(3))) unsigned int*)lds, 16, 0, 0);
}
__device__ __forceinline__ bf16x8 pack8bf(float4 lo, float4 hi) {
    bf16x8 r;
    r[0] = (short)f2bf(lo.x); r[1] = (short)f2bf(lo.y);
    r[2] = (short)f2bf(lo.z); r[3] = (short)f2bf(lo.w);
    r[4] = (short)f2bf(hi.x); r[5] = (short)f2bf(hi.y);
    r[6] = (short)f2bf(hi.z); r[7] = (short)f2bf(hi.w);
    return r;
}

// ---------------------------------------------------------------------------
// Kernel 1: transpose mean [100][4096] -> meanT [4096][100] (fp32)
// ---------------------------------------------------------------------------
__global__ __launch_bounds__(256) void k_meanT(const float* __restrict__ mean,
                                               float* __restrict__ meanT) {
    int i = blockIdx.x * 256 + threadIdx.x;
    if (i < D_ * N_POS_) {
        int d = i >> 12;
        int n = i & 4095;
        meanT[n * D_ + d] = mean[i];
    }
}

// ---------------------------------------------------------------------------
// Kernel 2: transpose combined [32 b][448 c][1024 pos] fp32
//        -> combT bf16 [pos*32 + b][448 c]   (rows of 896 B, contiguous)
// tile: 64 c x 64 pos per (b, ctile, ptile)
// ---------------------------------------------------------------------------
__global__ __launch_bounds__(256) void k_combT(const float* __restrict__ comb,
                                               unsigned short* __restrict__ combT) {
    __shared__ float T_[64][65];
    const int pt = blockIdx.x;      // 16 pos tiles (64 pos each)
    const int ct = blockIdx.y;      // 7 c tiles (64 c each)
    const int b  = blockIdx.z;      // 32
    const int t  = threadIdx.x;
    const int c0 = ct * 64, p0 = pt * 64;

    const float4* comb4 = (const float4*)comb;
#pragma unroll
    for (int k = 0; k < 4; k++) {
        int e4 = t + 256 * k;            // 1024 float4: [64 cc][16 p4]
        int cc = e4 >> 4, p4 = e4 & 15;
        float4 v = comb4[(b * C_COMB + c0 + cc) * 256 + pt * 16 + p4];
        T_[cc][p4 * 4 + 0] = v.x;
        T_[cc][p4 * 4 + 1] = v.y;
        T_[cc][p4 * 4 + 2] = v.z;
        T_[cc][p4 * 4 + 3] = v.w;
    }
    __syncthreads();
#pragma unroll
    for (int k = 0; k < 4; k++) {
        int e4 = t + 256 * k;            // 1024 uint2 writes: [64 pp][16 c4]
        int pp = e4 >> 4, c4 = e4 & 15;
        float f0 = T_[c4 * 4 + 0][pp];
        float f1 = T_[c4 * 4 + 1][pp];
        float f2 = T_[c4 * 4 + 2][pp];
        float f3 = T_[c4 * 4 + 3][pp];
        size_t R = (size_t)(p0 + pp) * 32 + b;
        *(uint2*)(combT + R * C_COMB + c0 + c4 * 4) =
            make_uint2(pack2bf(f0, f1), pack2bf(f2, f3));
    }
}

// ---------------------------------------------------------------------------
// Kernel 3: projection GEMM via MFMA:
//   p32[R][d] = sum_c W[d][c] * combT[R][c] + bias[d]   (R = pos*32+b)
// block: 64 R x 100 d; 4 waves, wave w handles R-cols [16w,16w+16)
// ---------------------------------------------------------------------------
__global__ __launch_bounds__(256) void k_proj(const unsigned short* __restrict__ combT,
                                              const float* __restrict__ W,
                                              const float* __restrict__ bias,
                                              unsigned short* __restrict__ p32b) {
    __shared__ unsigned short Bb[64 * C_COMB];   // 57344 B (DMA dest, contiguous)
    __shared__ unsigned short Ab[D_ * 32];       // 6400 B, [100 d][32 c-chunk]

    const int t = threadIdx.x;
    const int lane = t & 63, w = t >> 6;
    const int c = lane & 15, q = lane >> 4;
    const int R0 = blockIdx.x * 64;

    // DMA whole B slab: 64 rows x 448 bf16 = 57344 B = 3584 float4
    const unsigned short* gB = combT + (size_t)R0 * C_COMB;
#pragma unroll
    for (int k = 0; k < 14; k++) {
        int f4 = (k * 4 + w) * 64 + lane;
        async_copy16(gB + f4 * 8, Bb + f4 * 8);
    }

    f32x4 acc[7];
#pragma unroll
    for (int mt = 0; mt < 7; mt++) acc[mt] = (f32x4){0.f, 0.f, 0.f, 0.f};

    const float4* W4 = (const float4*)W;

    for (int kt = 0; kt < 14; kt++) {
        __syncthreads();   // drains DMA (kt=0) / protects Ab reuse
        // stage A chunk: W[100][kt*32 .. +32) fp32 -> bf16
#pragma unroll
        for (int k = 0; k < 4; k++) {
            int e4 = t + 256 * k;
            if (e4 < 800) {
                int rr = e4 >> 3, c4 = e4 & 7;
                float4 v = W4[rr * 112 + kt * 8 + c4];
                *(uint2*)(Ab + rr * 32 + c4 * 4) =
                    make_uint2(pack2bf(v.x, v.y), pack2bf(v.z, v.w));
            }
        }
        __syncthreads();

        bf16x8 bfrag = *(const bf16x8*)(Bb + (w * 16 + c) * C_COMB + kt * 32 + q * 8);
#pragma unroll
        for (int mt = 0; mt < 7; mt++) {
            int r = mt * 16 + c;
            bf16x8 afrag;
            if (r < D_) afrag = *(const bf16x8*)(Ab + r * 32 + q * 8);
            else        afrag = (bf16x8){0,0,0,0,0,0,0,0};
            acc[mt] = __builtin_amdgcn_mfma_f32_16x16x32_bf16(afrag, bfrag, acc[mt], 0, 0, 0);
        }
    }

    // epilogue: C[m=d][n=R-local]; col = lane&15, row = q*4+reg
    const int R = R0 + w * 16 + c;
#pragma unroll
    for (int mt = 0; mt < 7; mt++) {
        int d0 = mt * 16 + q * 4;
        if (d0 < D_) {
            f32x4 a = acc[mt];
            float o0 = a[0] + bias[d0 + 0];
            float o1 = a[1] + bias[d0 + 1];
            float o2 = a[2] + bias[d0 + 2];
            float o3 = a[3] + bias[d0 + 3];
            *(uint2*)(p32b + (size_t)R * D_ + d0) =
                make_uint2(pack2bf(o0, o1), pack2bf(o2, o3));
        }
    }
}

// ---------------------------------------------------------------------------
// Kernel 4: per n: bilinear 32->64 of p32 (bf16), mean subtract, Mahalanobis
// via MFMA. T=128 (2 waves); wave w handles batches [16w, 16w+16).
// ---------------------------------------------------------------------------
__global__ __launch_bounds__(128) void k_mahal(const unsigned short* __restrict__ p32b,
                                               const float* __restrict__ meanT,
                                               const float* __restrict__ icov,
                                               float* __restrict__ gdist) {
    __shared__ float Mf[D_ * D_];                 // 40000 B, contiguous (DMA dest)
    __shared__ unsigned short dTb[B_ * 104];      // 6656 B, [32 b][104 k] bf16

    const int n = blockIdx.x;
    const int t = threadIdx.x;
    const int lane = t & 63, w = t >> 6;
    const int c = lane & 15, q = lane >> 4;

    // ---- stage Sigma^-1[n]: 2500 float4 via DMA + tail ----
    const float* gM = icov + (size_t)n * (D_ * D_);
#pragma unroll
    for (int k = 0; k < 19; k++) {
        int f4 = k * 128 + w * 64 + lane;
        async_copy16(gM + f4 * 4, Mf + f4 * 4);
    }
    if (t < 68) {
        int f4 = 2432 + t;
        ((float4*)Mf)[f4] = ((const float4*)gM)[f4];
    }

    // ---- bilinear source setup (half-pixel, clamp) ----
    const int y = n >> 6, x = n & 63;
    float sy = 0.5f * y - 0.25f, sx = 0.5f * x - 0.25f;
    float y0f = floorf(sy), x0f = floorf(sx);
    float fy = sy - y0f, fx = sx - x0f;
    int iy0 = max((int)y0f, 0), iy1 = min((int)y0f + 1, 31);
    int ix0 = max((int)x0f, 0), ix1 = min((int)x0f + 1, 31);
    const float w00 = (1.f - fy) * (1.f - fx), w01 = (1.f - fy) * fx;
    const float w10 = fy * (1.f - fx),         w11 = fy * fx;
    const unsigned short* s00 = p32b + (size_t)(iy0 * 32 + ix0) * 3200;
    const unsigned short* s01 = p32b + (size_t)(iy0 * 32 + ix1) * 3200;
    const unsigned short* s10 = p32b + (size_t)(iy1 * 32 + ix0) * 3200;
    const unsigned short* s11 = p32b + (size_t)(iy1 * 32 + ix1) * 3200;

    // ---- build dTb[b][d] bf16: 800 groups of 4 d ----
    const float4* mt4 = (const float4*)meanT + n * 25;
#pragma unroll
    for (int k = 0; k < 7; k++) {
        int e4 = t + 128 * k;
        if (e4 < 800) {
            int b  = e4 / 25;
            int d4 = e4 - b * 25;
            float4 f00 = bf4_to_f4(*(const uint2*)(s00 + e4 * 4));
            float4 f01 = bf4_to_f4(*(const uint2*)(s01 + e4 * 4));
            float4 f10 = bf4_to_f4(*(const uint2*)(s10 + e4 * 4));
            float4 f11 = bf4_to_f4(*(const uint2*)(s11 + e4 * 4));
            float4 m = mt4[d4];
            float vx = w00 * f00.x + w01 * f01.x + w10 * f10.x + w11 * f11.x - m.x;
            float vy = w00 * f00.y + w01 * f01.y + w10 * f10.y + w11 * f11.y - m.y;
            float vz = w00 * f00.z + w01 * f01.z + w10 * f10.z + w11 * f11.z - m.z;
            float vw = w00 * f00.w + w01 * f01.w + w10 * f10.w + w11 * f11.w - m.w;
            *(uint2*)(dTb + b * 104 + d4 * 4) =
                make_uint2(pack2bf(vx, vy), pack2bf(vz, vw));
        }
    }
    if (t < 32) *(uint2*)(dTb + t * 104 + 100) = make_uint2(0u, 0u);  // k-pad

    __syncthreads();   // drains DMA + LDS writes

    // ---- MFMA: Y[i][b] = sum_j M[i][j] * d[j][b] ----
    const int bb = w * 16 + c;     // this lane's batch (C column)
    f32x4 acc[7];
#pragma unroll
    for (int mt = 0; mt < 7; mt++) acc[mt] = (f32x4){0.f, 0.f, 0.f, 0.f};

#pragma unroll
    for (int kt = 0; kt < 4; kt++) {
        int k0 = kt * 32 + q * 8;
        bf16x8 bfrag;
        if (k0 < 104) bfrag = *(const bf16x8*)(dTb + bb * 104 + k0);
        else          bfrag = (bf16x8){0,0,0,0,0,0,0,0};
#pragma unroll
        for (int mt = 0; mt < 7; mt++) {
            int r = mt * 16 + c;
            bf16x8 afrag;
            if (r < D_ && k0 < D_) {
                const float* src = Mf + r * D_ + k0;
                float4 lo = *(const float4*)(src);
                float4 hi;
                if (k0 + 7 < D_) hi = *(const float4*)(src + 4);
                else             hi = (float4){0.f, 0.f, 0.f, 0.f};
                afrag = pack8bf(lo, hi);
            } else {
                afrag = (bf16x8){0,0,0,0,0,0,0,0};
            }
            acc[mt] = __builtin_amdgcn_mfma_f32_16x16x32_bf16(afrag, bfrag, acc[mt], 0, 0, 0);
        }
    }

    // ---- fold: dist_b = sum_i d[b][i] * Y[i][b] ----
    float dist = 0.f;
#pragma unroll
    for (int mt = 0; mt < 7; mt++) {
#pragma unroll
        for (int reg = 0; reg < 4; reg++) {
            int r = mt * 16 + q * 4 + reg;
            if (r < D_) dist += acc[mt][reg] * bf2f(dTb[bb * 104 + r]);
        }
    }
    dist += __shfl_xor(dist, 16);
    dist += __shfl_xor(dist, 32);
    if (q == 0) gdist[bb * N_POS_ + n] = dist;
}

// ---------------------------------------------------------------------------
// Kernel 5: 4x bilinear upsample 64->256 + normalize
// ---------------------------------------------------------------------------
__global__ __launch_bounds__(256) void k_upsample(const float* __restrict__ gdist,
                                                  const float* __restrict__ nminp,
                                                  const float* __restrict__ nmaxp,
                                                  float* __restrict__ out) {
    int gid = blockIdx.x * 256 + threadIdx.x;
    int b   = gid >> 16;
    int rem = gid & 65535;
    int Y = rem >> 8, X = rem & 255;
    float sy = 0.25f * Y - 0.375f, sx = 0.25f * X - 0.375f;
    float y0f = floorf(sy), x0f = floorf(sx);
    float fy = sy - y0f, fx = sx - x0f;
    int iy0 = max((int)y0f, 0), iy1 = min((int)y0f + 1, 63);
    int ix0 = max((int)x0f, 0), ix1 = min((int)x0f + 1, 63);
    const float* g = gdist + b * N_POS_;
    float v00 = g[iy0 * 64 + ix0], v01 = g[iy0 * 64 + ix1];
    float v10 = g[iy1 * 64 + ix0], v11 = g[iy1 * 64 + ix1];
    float v = (1.f - fy) * ((1.f - fx) * v00 + fx * v01)
            +        fy  * ((1.f - fx) * v10 + fx * v11);
    float nmin = nminp[0], nmax = nmaxp[0];
    float scale = 1.0f / (nmax - nmin + 1e-8f);
    out[gid] = (v - nmin) * scale;
}

// ---------------------------------------------------------------------------
extern "C" void kernel_launch(void* const* d_in, const int* in_sizes, int n_in,
                              void* d_out, int out_size, void* d_ws, size_t ws_size,
                              hipStream_t stream) {
    const float* comb = (const float*)d_in[0];
    const float* W    = (const float*)d_in[1];
    const float* bias = (const float*)d_in[2];
    const float* mean = (const float*)d_in[3];
    const float* icov = (const float*)d_in[4];
    const float* nmin = (const float*)d_in[5];
    const float* nmax = (const float*)d_in[6];
    float* out = (float*)d_out;

    char* ws = (char*)d_ws;
    // combT: 32768*448*2 = 29,360,128 B   (dead after k_proj; gdist aliases base)
    unsigned short* combT = (unsigned short*)(ws);
    float*          gdist = (float*)(ws);                       // 524,288 B (alias)
    unsigned short* p32b  = (unsigned short*)(ws + 29360128);   // 6,553,600 B
    float*          meanT = (float*)(ws + 29360128 + 6553600);  // 1,638,400 B

    k_meanT   <<<1600, 256, 0, stream>>>(mean, meanT);
    k_combT   <<<dim3(16, 7, 32), 256, 0, stream>>>(comb, combT);
    k_proj    <<<512, 256, 0, stream>>>(combT, W, bias, p32b);
    k_mahal   <<<4096, 128, 0, stream>>>(p32b, meanT, icov, gdist);
    k_upsample<<<8192, 256, 0, stream>>>(gdist, nmin, nmax, out);
}

// Round 3
// 317.080 us; speedup vs baseline: 1.3813x; 1.1046x over previous
//
#include <hip/hip_runtime.h>

#define B_      32
#define C_COMB  448
#define N_POS_  4096
#define D_      100

typedef __attribute__((ext_vector_type(8))) short bf16x8;
typedef __attribute__((ext_vector_type(4))) float f32x4;

// ---------------- bf16 helpers (RNE) ----------------
__device__ __forceinline__ unsigned short f2bf(float f) {
    unsigned u = __builtin_bit_cast(unsigned, f);
    u += 0x7FFFu + ((u >> 16) & 1u);
    return (unsigned short)(u >> 16);
}
__device__ __forceinline__ unsigned pack2bf(float a, float b) {
    return (unsigned)f2bf(a) | ((unsigned)f2bf(b) << 16);
}
__device__ __forceinline__ float bf2f(unsigned short h) {
    return __builtin_bit_cast(float, (unsigned)h << 16);
}
__device__ __forceinline__ float4 bf4_to_f4(uint2 u) {
    float4 r;
    r.x = __builtin_bit_cast(float, u.x << 16);
    r.y = __builtin_bit_cast(float, u.x & 0xffff0000u);
    r.z = __builtin_bit_cast(float, u.y << 16);
    r.w = __builtin_bit_cast(float, u.y & 0xffff0000u);
    return r;
}

// ---------------------------------------------------------------------------
// Kernel 1: prep — W fp32 -> Wb bf16 (contiguous [100][448]) and
//           mean [100][4096] -> meanT [4096][100] fp32
// ---------------------------------------------------------------------------
__global__ __launch_bounds__(256) void k_prep(const float* __restrict__ W,
                                              unsigned short* __restrict__ Wb,
                                              const float* __restrict__ mean,
                                              float* __restrict__ meanT) {
    int i = blockIdx.x * 256 + threadIdx.x;
    if (i < 11200) {                       // 44800 floats as f4
        float4 v = ((const float4*)W)[i];
        ((uint2*)Wb)[i] = make_uint2(pack2bf(v.x, v.y), pack2bf(v.z, v.w));
    }
    if (i < D_ * N_POS_) {
        int d = i >> 12;
        int n = i & 4095;
        meanT[n * D_ + d] = mean[i];
    }
}

// ---------------------------------------------------------------------------
// Kernel 2: fused projection GEMM (no combT materialization):
//   p32[pos][b][d] = sum_c W[d][c] * comb[b][c][pos] + bias[d]
// grid (16 pos-tiles of 64, 32 b), 256 thr. Per kt=32c: stage comb tile
// [32c][64p] fp32 in LDS (pad 65 -> B-frag scalar reads are 2-way/free),
// stage W chunk bf16 [100][40] (pad -> b128 A-frags 2-way/free).
// ---------------------------------------------------------------------------
__global__ __launch_bounds__(256) void k_proj(const float* __restrict__ comb,
                                              const unsigned short* __restrict__ Wb,
                                              const float* __restrict__ bias,
                                              unsigned short* __restrict__ p32b) {
    __shared__ float Tf[32 * 65];            // 8320 B, [cc][p] pad 65
    __shared__ unsigned short Ws[D_ * 40];   // 8000 B, [d][kk] pad 40

    const int pt = blockIdx.x, b = blockIdx.y;
    const int t = threadIdx.x;
    const int lane = t & 63, w = t >> 6;
    const int c = lane & 15, q = lane >> 4;

    f32x4 acc[7];
#pragma unroll
    for (int mt = 0; mt < 7; mt++) acc[mt] = (f32x4){0.f, 0.f, 0.f, 0.f};

    const float4* comb4 = (const float4*)comb;

    for (int kt = 0; kt < 14; kt++) {
        __syncthreads();
        // comb tile: 512 f4, coalesced; scalar LDS stores (conflict-free)
#pragma unroll
        for (int k = 0; k < 2; k++) {
            int e4 = t + 256 * k;
            int cc = e4 >> 4, p4 = e4 & 15;
            float4 v = comb4[((size_t)b * C_COMB + kt * 32 + cc) * 256 + pt * 16 + p4];
            Tf[cc * 65 + p4 * 4 + 0] = v.x;
            Tf[cc * 65 + p4 * 4 + 1] = v.y;
            Tf[cc * 65 + p4 * 4 + 2] = v.z;
            Tf[cc * 65 + p4 * 4 + 3] = v.w;
        }
        // W chunk: 800 uint2 raw copies (already bf16)
#pragma unroll
        for (int k = 0; k < 4; k++) {
            int e = t + 256 * k;
            if (e < 800) {
                int d = e >> 3, c4 = e & 7;
                *(uint2*)(Ws + d * 40 + c4 * 4) =
                    *(const uint2*)(Wb + d * C_COMB + kt * 32 + c4 * 4);
            }
        }
        __syncthreads();

        // B-frag: lane (c,q) needs comb[k=q*8+j][pos=w*16+c], j=0..7
        bf16x8 bfrag;
#pragma unroll
        for (int j = 0; j < 8; j++) {
            bfrag[j] = (short)f2bf(Tf[(q * 8 + j) * 65 + w * 16 + c]);
        }
#pragma unroll
        for (int mt = 0; mt < 7; mt++) {
            int r = mt * 16 + c;
            bf16x8 afrag;
            if (r < D_) afrag = *(const bf16x8*)(Ws + r * 40 + q * 8);
            else        afrag = (bf16x8){0,0,0,0,0,0,0,0};
            acc[mt] = __builtin_amdgcn_mfma_f32_16x16x32_bf16(afrag, bfrag, acc[mt], 0, 0, 0);
        }
    }

    // epilogue: C[m=d][n=pos-local]; col=lane&15, row=q*4+reg
    const int pos = pt * 64 + w * 16 + c;
#pragma unroll
    for (int mt = 0; mt < 7; mt++) {
        int d0 = mt * 16 + q * 4;
        if (d0 < D_) {
            f32x4 a = acc[mt];
            float o0 = a[0] + bias[d0 + 0];
            float o1 = a[1] + bias[d0 + 1];
            float o2 = a[2] + bias[d0 + 2];
            float o3 = a[3] + bias[d0 + 3];
            *(uint2*)(p32b + ((size_t)pos * B_ + b) * D_ + d0) =
                make_uint2(pack2bf(o0, o1), pack2bf(o2, o3));
        }
    }
}

// ---------------------------------------------------------------------------
// Kernel 3: per n: bilinear 32->64 of p32 (bf16), mean subtract, Mahalanobis
// via MFMA. 256 thr / 4 waves; wave = (batch-half g, row-half h).
// Sigma^-1 staged as bf16 in LDS (20.8 KB) -> 5 blocks/CU, 20 waves/CU.
// ---------------------------------------------------------------------------
__global__ __launch_bounds__(256) void k_mahal(const unsigned short* __restrict__ p32b,
                                               const float* __restrict__ meanT,
                                               const float* __restrict__ icov,
                                               float* __restrict__ gdist) {
    __shared__ unsigned short Mb[D_ * 104];     // 20800 B, [100 r][104 k] bf16
    __shared__ unsigned short dTb[B_ * 104];    // 6656 B,  [32 b][104 k] bf16
    __shared__ float part[64];                  // [4 waves][16]

    const int n = blockIdx.x;
    const int t = threadIdx.x;
    const int lane = t & 63, w = t >> 6;
    const int c = lane & 15, q = lane >> 4;

    // zero k-pads (cols 100..103)
    if (t < 100) *(uint2*)(Mb + t * 104 + 100) = make_uint2(0u, 0u);
    if (t >= 128 && t < 160) *(uint2*)(dTb + (t - 128) * 104 + 100) = make_uint2(0u, 0u);

    // ---- stage Sigma^-1[n] fp32 -> bf16 LDS: 2500 f4, coalesced ----
    const float4* gM4 = (const float4*)(icov + (size_t)n * (D_ * D_));
#pragma unroll
    for (int k = 0; k < 10; k++) {
        int e4 = t + 256 * k;
        if (e4 < 2500) {
            float4 v = gM4[e4];
            int r = e4 / 25, c4 = e4 - r * 25;
            *(uint2*)(Mb + r * 104 + c4 * 4) =
                make_uint2(pack2bf(v.x, v.y), pack2bf(v.z, v.w));
        }
    }

    // ---- bilinear source setup (half-pixel, clamp) ----
    const int y = n >> 6, x = n & 63;
    float sy = 0.5f * y - 0.25f, sx = 0.5f * x - 0.25f;
    float y0f = floorf(sy), x0f = floorf(sx);
    float fy = sy - y0f, fx = sx - x0f;
    int iy0 = max((int)y0f, 0), iy1 = min((int)y0f + 1, 31);
    int ix0 = max((int)x0f, 0), ix1 = min((int)x0f + 1, 31);
    const float w00 = (1.f - fy) * (1.f - fx), w01 = (1.f - fy) * fx;
    const float w10 = fy * (1.f - fx),         w11 = fy * fx;
    const unsigned short* s00 = p32b + (size_t)(iy0 * 32 + ix0) * 3200;
    const unsigned short* s01 = p32b + (size_t)(iy0 * 32 + ix1) * 3200;
    const unsigned short* s10 = p32b + (size_t)(iy1 * 32 + ix0) * 3200;
    const unsigned short* s11 = p32b + (size_t)(iy1 * 32 + ix1) * 3200;

    // ---- build dTb[b][d] bf16: 800 groups of 4 d ----
    const float4* mt4 = (const float4*)meanT + n * 25;
#pragma unroll
    for (int k = 0; k < 4; k++) {
        int e4 = t + 256 * k;
        if (e4 < 800) {
            int b  = e4 / 25;
            int d4 = e4 - b * 25;
            float4 f00 = bf4_to_f4(*(const uint2*)(s00 + e4 * 4));
            float4 f01 = bf4_to_f4(*(const uint2*)(s01 + e4 * 4));
            float4 f10 = bf4_to_f4(*(const uint2*)(s10 + e4 * 4));
            float4 f11 = bf4_to_f4(*(const uint2*)(s11 + e4 * 4));
            float4 m = mt4[d4];
            float vx = w00 * f00.x + w01 * f01.x + w10 * f10.x + w11 * f11.x - m.x;
            float vy = w00 * f00.y + w01 * f01.y + w10 * f10.y + w11 * f11.y - m.y;
            float vz = w00 * f00.z + w01 * f01.z + w10 * f10.z + w11 * f11.z - m.z;
            float vw = w00 * f00.w + w01 * f01.w + w10 * f10.w + w11 * f11.w - m.w;
            *(uint2*)(dTb + b * 104 + d4 * 4) =
                make_uint2(pack2bf(vx, vy), pack2bf(vz, vw));
        }
    }
    __syncthreads();

    // ---- MFMA: Y[i][b] = sum_j M[i][j] d[j][b]; wave = (g=batch-half, h=row-half)
    const int g = w & 1, h = w >> 1;
    const int bb = g * 16 + c;
    const int mt0 = h * 4;                  // rows mt0..mt0+3 (h=1: 4..6)
    f32x4 acc[4];
#pragma unroll
    for (int mi = 0; mi < 4; mi++) acc[mi] = (f32x4){0.f, 0.f, 0.f, 0.f};

#pragma unroll
    for (int kt = 0; kt < 4; kt++) {
        int k0 = kt * 32 + q * 8;
        bf16x8 bfrag;
        if (k0 < 104) bfrag = *(const bf16x8*)(dTb + bb * 104 + k0);
        else          bfrag = (bf16x8){0,0,0,0,0,0,0,0};
#pragma unroll
        for (int mi = 0; mi < 4; mi++) {
            int mt = mt0 + mi;
            if (mt >= 7) continue;
            int r = mt * 16 + c;
            bf16x8 afrag;
            if (r < D_ && k0 < 104) afrag = *(const bf16x8*)(Mb + r * 104 + k0);
            else                    afrag = (bf16x8){0,0,0,0,0,0,0,0};
            acc[mi] = __builtin_amdgcn_mfma_f32_16x16x32_bf16(afrag, bfrag, acc[mi], 0, 0, 0);
        }
    }

    // ---- fold: dist_b partial over this wave's rows ----
    float dist = 0.f;
#pragma unroll
    for (int mi = 0; mi < 4; mi++) {
        int mt = mt0 + mi;
        if (mt >= 7) continue;
#pragma unroll
        for (int reg = 0; reg < 4; reg++) {
            int r = mt * 16 + q * 4 + reg;
            if (r < D_) dist += acc[mi][reg] * bf2f(dTb[bb * 104 + r]);
        }
    }
    dist += __shfl_xor(dist, 16);
    dist += __shfl_xor(dist, 32);
    if (q == 0) part[w * 16 + c] = dist;
    __syncthreads();
    if (t < 32) {
        int gg = t >> 4, cc = t & 15;
        float s = part[gg * 16 + cc] + part[(gg + 2) * 16 + cc];
        gdist[t * N_POS_ + n] = s;
    }
}

// ---------------------------------------------------------------------------
// Kernel 4: 4x bilinear upsample 64->256 + normalize
// ---------------------------------------------------------------------------
__global__ __launch_bounds__(256) void k_upsample(const float* __restrict__ gdist,
                                                  const float* __restrict__ nminp,
                                                  const float* __restrict__ nmaxp,
                                                  float* __restrict__ out) {
    int gid = blockIdx.x * 256 + threadIdx.x;
    int b   = gid >> 16;
    int rem = gid & 65535;
    int Y = rem >> 8, X = rem & 255;
    float sy = 0.25f * Y - 0.375f, sx = 0.25f * X - 0.375f;
    float y0f = floorf(sy), x0f = floorf(sx);
    float fy = sy - y0f, fx = sx - x0f;
    int iy0 = max((int)y0f, 0), iy1 = min((int)y0f + 1, 63);
    int ix0 = max((int)x0f, 0), ix1 = min((int)x0f + 1, 63);
    const float* g = gdist + b * N_POS_;
    float v00 = g[iy0 * 64 + ix0], v01 = g[iy0 * 64 + ix1];
    float v10 = g[iy1 * 64 + ix0], v11 = g[iy1 * 64 + ix1];
    float v = (1.f - fy) * ((1.f - fx) * v00 + fx * v01)
            +        fy  * ((1.f - fx) * v10 + fx * v11);
    float nmin = nminp[0], nmax = nmaxp[0];
    float scale = 1.0f / (nmax - nmin + 1e-8f);
    out[gid] = (v - nmin) * scale;
}

// ---------------------------------------------------------------------------
extern "C" void kernel_launch(void* const* d_in, const int* in_sizes, int n_in,
                              void* d_out, int out_size, void* d_ws, size_t ws_size,
                              hipStream_t stream) {
    const float* comb = (const float*)d_in[0];
    const float* W    = (const float*)d_in[1];
    const float* bias = (const float*)d_in[2];
    const float* mean = (const float*)d_in[3];
    const float* icov = (const float*)d_in[4];
    const float* nmin = (const float*)d_in[5];
    const float* nmax = (const float*)d_in[6];
    float* out = (float*)d_out;

    char* ws = (char*)d_ws;
    unsigned short* p32b  = (unsigned short*)(ws);            //  6,553,600 B
    float*          meanT = (float*)(ws + 6553600);           //  1,638,400 B
    unsigned short* Wb    = (unsigned short*)(ws + 8192000);  //     89,600 B
    float*          gdist = (float*)(ws + 8281600);           //    524,288 B

    k_prep    <<<1600, 256, 0, stream>>>(W, Wb, mean, meanT);
    k_proj    <<<dim3(16, 32), 256, 0, stream>>>(comb, Wb, bias, p32b);
    k_mahal   <<<4096, 256, 0, stream>>>(p32b, meanT, icov, gdist);
    k_upsample<<<8192, 256, 0, stream>>>(gdist, nmin, nmax, out);
}

// Round 4
// 310.036 us; speedup vs baseline: 1.4127x; 1.0227x over previous
//
#include <hip/hip_runtime.h>

#define B_      32
#define C_COMB  448
#define N_POS_  4096
#define D_      100

typedef __attribute__((ext_vector_type(8)))  short bf16x8;
typedef __attribute__((ext_vector_type(4)))  float f32x4;
typedef __attribute__((ext_vector_type(16))) float f32x16;

// ---------------- bf16 helpers (RNE) ----------------
__device__ __forceinline__ unsigned short f2bf(float f) {
    unsigned u = __builtin_bit_cast(unsigned, f);
    u += 0x7FFFu + ((u >> 16) & 1u);
    return (unsigned short)(u >> 16);
}
__device__ __forceinline__ unsigned pack2bf(float a, float b) {
    return (unsigned)f2bf(a) | ((unsigned)f2bf(b) << 16);
}
__device__ __forceinline__ float bf2f(unsigned short h) {
    return __builtin_bit_cast(float, (unsigned)h << 16);
}
__device__ __forceinline__ float4 bf4_to_f4(uint2 u) {
    float4 r;
    r.x = __builtin_bit_cast(float, u.x << 16);
    r.y = __builtin_bit_cast(float, u.x & 0xffff0000u);
    r.z = __builtin_bit_cast(float, u.y << 16);
    r.w = __builtin_bit_cast(float, u.y & 0xffff0000u);
    return r;
}
__device__ __forceinline__ bf16x8 pack8bf(float4 lo, float4 hi) {
    bf16x8 r;
    r[0] = (short)f2bf(lo.x); r[1] = (short)f2bf(lo.y);
    r[2] = (short)f2bf(lo.z); r[3] = (short)f2bf(lo.w);
    r[4] = (short)f2bf(hi.x); r[5] = (short)f2bf(hi.y);
    r[6] = (short)f2bf(hi.z); r[7] = (short)f2bf(hi.w);
    return r;
}

// ---------------------------------------------------------------------------
// Kernel 1: prep — W fp32 -> Wb bf16 (contiguous [100][448])
// ---------------------------------------------------------------------------
__global__ __launch_bounds__(256) void k_prep(const float* __restrict__ W,
                                              unsigned short* __restrict__ Wb) {
    int i = blockIdx.x * 256 + threadIdx.x;
    if (i < 11200) {                       // 44800 floats as f4
        float4 v = ((const float4*)W)[i];
        ((uint2*)Wb)[i] = make_uint2(pack2bf(v.x, v.y), pack2bf(v.z, v.w));
    }
}

// ---------------------------------------------------------------------------
// Kernel 2: fused projection GEMM (unchanged from R3):
//   p32[pos][b][d] = sum_c W[d][c] * comb[b][c][pos] + bias[d]
// ---------------------------------------------------------------------------
__global__ __launch_bounds__(256) void k_proj(const float* __restrict__ comb,
                                              const unsigned short* __restrict__ Wb,
                                              const float* __restrict__ bias,
                                              unsigned short* __restrict__ p32b) {
    __shared__ float Tf[32 * 65];            // 8320 B, [cc][p] pad 65
    __shared__ unsigned short Ws[D_ * 40];   // 8000 B, [d][kk] pad 40

    const int pt = blockIdx.x, b = blockIdx.y;
    const int t = threadIdx.x;
    const int lane = t & 63, w = t >> 6;
    const int c = lane & 15, q = lane >> 4;

    f32x4 acc[7];
#pragma unroll
    for (int mt = 0; mt < 7; mt++) acc[mt] = (f32x4){0.f, 0.f, 0.f, 0.f};

    const float4* comb4 = (const float4*)comb;

    for (int kt = 0; kt < 14; kt++) {
        __syncthreads();
#pragma unroll
        for (int k = 0; k < 2; k++) {
            int e4 = t + 256 * k;
            int cc = e4 >> 4, p4 = e4 & 15;
            float4 v = comb4[((size_t)b * C_COMB + kt * 32 + cc) * 256 + pt * 16 + p4];
            Tf[cc * 65 + p4 * 4 + 0] = v.x;
            Tf[cc * 65 + p4 * 4 + 1] = v.y;
            Tf[cc * 65 + p4 * 4 + 2] = v.z;
            Tf[cc * 65 + p4 * 4 + 3] = v.w;
        }
#pragma unroll
        for (int k = 0; k < 4; k++) {
            int e = t + 256 * k;
            if (e < 800) {
                int d = e >> 3, c4 = e & 7;
                *(uint2*)(Ws + d * 40 + c4 * 4) =
                    *(const uint2*)(Wb + d * C_COMB + kt * 32 + c4 * 4);
            }
        }
        __syncthreads();

        bf16x8 bfrag;
#pragma unroll
        for (int j = 0; j < 8; j++) {
            bfrag[j] = (short)f2bf(Tf[(q * 8 + j) * 65 + w * 16 + c]);
        }
#pragma unroll
        for (int mt = 0; mt < 7; mt++) {
            int r = mt * 16 + c;
            bf16x8 afrag;
            if (r < D_) afrag = *(const bf16x8*)(Ws + r * 40 + q * 8);
            else        afrag = (bf16x8){0,0,0,0,0,0,0,0};
            acc[mt] = __builtin_amdgcn_mfma_f32_16x16x32_bf16(afrag, bfrag, acc[mt], 0, 0, 0);
        }
    }

    const int pos = pt * 64 + w * 16 + c;
#pragma unroll
    for (int mt = 0; mt < 7; mt++) {
        int d0 = mt * 16 + q * 4;
        if (d0 < D_) {
            f32x4 a = acc[mt];
            float o0 = a[0] + bias[d0 + 0];
            float o1 = a[1] + bias[d0 + 1];
            float o2 = a[2] + bias[d0 + 2];
            float o3 = a[3] + bias[d0 + 3];
            *(uint2*)(p32b + ((size_t)pos * B_ + b) * D_ + d0) =
                make_uint2(pack2bf(o0, o1), pack2bf(o2, o3));
        }
    }
}

// ---------------------------------------------------------------------------
// Kernel 3: per n: bilinear 32->64 of p32 (bf16), mean subtract, Mahalanobis.
// 32x32x16 MFMA; Sigma^-1 read from global DIRECTLY into A-fragments
// (each element exactly once chip-wide; no LDS staging). LDS ~7.8 KB ->
// 8 blocks/CU (wave-capped), 32 waves hiding the icov stream.
// ---------------------------------------------------------------------------
__global__ __launch_bounds__(256) void k_mahal(const unsigned short* __restrict__ p32b,
                                               const float* __restrict__ mean,
                                               const float* __restrict__ icov,
                                               float* __restrict__ gdist) {
    __shared__ unsigned short dTb[B_ * 104];   // 6656 B, [32 b][104 k] bf16
    __shared__ float meanL[112];               // 100 used (16B-aligned reads)
    __shared__ float part[128];                // [4 waves][32 b]

    const int n = blockIdx.x;
    const int t = threadIdx.x;
    const int lane = t & 63, w = t >> 6;
    const int half = lane >> 5;                // k-half within wave
    const int l31  = lane & 31;

    // mean[d][n] -> meanL (scalar, stride 16KB; L2-hot: each line reused by 64 n)
    if (t < 100) meanL[t] = mean[t * N_POS_ + n];
    if (t >= 128 && t < 160) *(uint2*)(dTb + (t - 128) * 104 + 100) = make_uint2(0u, 0u);

    // bilinear 32->64 source (half-pixel, clamp)
    const int y = n >> 6, x = n & 63;
    float sy = 0.5f * y - 0.25f, sx = 0.5f * x - 0.25f;
    float y0f = floorf(sy), x0f = floorf(sx);
    float fy = sy - y0f, fx = sx - x0f;
    int iy0 = max((int)y0f, 0), iy1 = min((int)y0f + 1, 31);
    int ix0 = max((int)x0f, 0), ix1 = min((int)x0f + 1, 31);
    const float w00 = (1.f - fy) * (1.f - fx), w01 = (1.f - fy) * fx;
    const float w10 = fy * (1.f - fx),         w11 = fy * fx;
    const unsigned short* s00 = p32b + (size_t)(iy0 * 32 + ix0) * 3200;
    const unsigned short* s01 = p32b + (size_t)(iy0 * 32 + ix1) * 3200;
    const unsigned short* s10 = p32b + (size_t)(iy1 * 32 + ix0) * 3200;
    const unsigned short* s11 = p32b + (size_t)(iy1 * 32 + ix1) * 3200;

    __syncthreads();   // meanL visible

    // build dTb[b][d] bf16: 800 groups of 4 d
#pragma unroll
    for (int k = 0; k < 4; k++) {
        int e4 = t + 256 * k;
        if (e4 < 800) {
            int b  = e4 / 25;
            int d4 = e4 - b * 25;
            float4 f00 = bf4_to_f4(*(const uint2*)(s00 + e4 * 4));
            float4 f01 = bf4_to_f4(*(const uint2*)(s01 + e4 * 4));
            float4 f10 = bf4_to_f4(*(const uint2*)(s10 + e4 * 4));
            float4 f11 = bf4_to_f4(*(const uint2*)(s11 + e4 * 4));
            float4 m = *(const float4*)(meanL + d4 * 4);
            float vx = w00 * f00.x + w01 * f01.x + w10 * f10.x + w11 * f11.x - m.x;
            float vy = w00 * f00.y + w01 * f01.y + w10 * f10.y + w11 * f11.y - m.y;
            float vz = w00 * f00.z + w01 * f01.z + w10 * f10.z + w11 * f11.z - m.z;
            float vw = w00 * f00.w + w01 * f01.w + w10 * f10.w + w11 * f11.w - m.w;
            *(uint2*)(dTb + b * 104 + d4 * 4) =
                make_uint2(pack2bf(vx, vy), pack2bf(vz, vw));
        }
    }
    __syncthreads();   // dTb visible

    // ---- MFMA 32x32x16: Y[r][b]; wave w owns rows 32w..32w+31 ----
    // A layout: m = lane&31, k = (lane>>5)*8 + j  (mirrors verified 16x16x32)
    const int r = 32 * w + l31;
    const bool rv = (r < D_);
    const float* Mrow = icov + (size_t)n * (D_ * D_) + (size_t)r * D_;

    f32x16 acc = {0.f,0.f,0.f,0.f,0.f,0.f,0.f,0.f,0.f,0.f,0.f,0.f,0.f,0.f,0.f,0.f};
#pragma unroll
    for (int kt = 0; kt < 7; kt++) {
        int k0 = kt * 16 + half * 8;
        bf16x8 afrag;
        if (rv && k0 < D_) {
            float4 lo = *(const float4*)(Mrow + k0);
            float4 hi;
            if (k0 + 4 < D_) hi = *(const float4*)(Mrow + k0 + 4);
            else             hi = (float4){0.f, 0.f, 0.f, 0.f};
            afrag = pack8bf(lo, hi);
        } else {
            afrag = (bf16x8){0,0,0,0,0,0,0,0};
        }
        bf16x8 bfrag;
        if (k0 < D_) bfrag = *(const bf16x8*)(dTb + l31 * 104 + k0);
        else         bfrag = (bf16x8){0,0,0,0,0,0,0,0};
        acc = __builtin_amdgcn_mfma_f32_32x32x16_bf16(afrag, bfrag, acc, 0, 0, 0);
    }

    // ---- fold: dist_b += Y[rr][b] * d[b][rr] over this wave's rows ----
    // C/D layout (verified m74/m101): col=lane&31, row=(reg&3)+8*(reg>>2)+4*(lane>>5)
    float dist = 0.f;
#pragma unroll
    for (int reg = 0; reg < 16; reg++) {
        int rr = 32 * w + (reg & 3) + 8 * (reg >> 2) + 4 * half;
        if (rr < D_) dist += acc[reg] * bf2f(dTb[l31 * 104 + rr]);
    }
    dist += __shfl_xor(dist, 32);
    if (half == 0) part[w * 32 + l31] = dist;
    __syncthreads();
    if (t < 32) {
        float s = part[t] + part[32 + t] + part[64 + t] + part[96 + t];
        gdist[t * N_POS_ + n] = s;
    }
}

// ---------------------------------------------------------------------------
// Kernel 4: 4x bilinear upsample 64->256 + normalize
// ---------------------------------------------------------------------------
__global__ __launch_bounds__(256) void k_upsample(const float* __restrict__ gdist,
                                                  const float* __restrict__ nminp,
                                                  const float* __restrict__ nmaxp,
                                                  float* __restrict__ out) {
    int gid = blockIdx.x * 256 + threadIdx.x;
    int b   = gid >> 16;
    int rem = gid & 65535;
    int Y = rem >> 8, X = rem & 255;
    float sy = 0.25f * Y - 0.375f, sx = 0.25f * X - 0.375f;
    float y0f = floorf(sy), x0f = floorf(sx);
    float fy = sy - y0f, fx = sx - x0f;
    int iy0 = max((int)y0f, 0), iy1 = min((int)y0f + 1, 63);
    int ix0 = max((int)x0f, 0), ix1 = min((int)x0f + 1, 63);
    const float* g = gdist + b * N_POS_;
    float v00 = g[iy0 * 64 + ix0], v01 = g[iy0 * 64 + ix1];
    float v10 = g[iy1 * 64 + ix0], v11 = g[iy1 * 64 + ix1];
    float v = (1.f - fy) * ((1.f - fx) * v00 + fx * v01)
            +        fy  * ((1.f - fx) * v10 + fx * v11);
    float nmin = nminp[0], nmax = nmaxp[0];
    float scale = 1.0f / (nmax - nmin + 1e-8f);
    out[gid] = (v - nmin) * scale;
}

// ---------------------------------------------------------------------------
extern "C" void kernel_launch(void* const* d_in, const int* in_sizes, int n_in,
                              void* d_out, int out_size, void* d_ws, size_t ws_size,
                              hipStream_t stream) {
    const float* comb = (const float*)d_in[0];
    const float* W    = (const float*)d_in[1];
    const float* bias = (const float*)d_in[2];
    const float* mean = (const float*)d_in[3];
    const float* icov = (const float*)d_in[4];
    const float* nmin = (const float*)d_in[5];
    const float* nmax = (const float*)d_in[6];
    float* out = (float*)d_out;

    char* ws = (char*)d_ws;
    unsigned short* p32b  = (unsigned short*)(ws);            //  6,553,600 B
    unsigned short* Wb    = (unsigned short*)(ws + 6553600);  //     89,600 B
    float*          gdist = (float*)(ws + 6643200);           //    524,288 B

    k_prep    <<<44, 256, 0, stream>>>(W, Wb);
    k_proj    <<<dim3(16, 32), 256, 0, stream>>>(comb, Wb, bias, p32b);
    k_mahal   <<<4096, 256, 0, stream>>>(p32b, mean, icov, gdist);
    k_upsample<<<8192, 256, 0, stream>>>(gdist, nmin, nmax, out);
}